// Round 1
// baseline (1257.027 us; speedup 1.0000x reference)
//
#include <hip/hip_runtime.h>

// Binary_49950469653358: gather-2 -> [32x64]@[64x512] + bias -> l2norm(d) -> store
// N_SYMBOLS=128, D_WORLDS=32, N_WORLDS=512, BATCH=2048, N_STEPS=8
// Memory-bound: ~402 MB mandatory HBM traffic -> ~64 us floor at 6.3 TB/s.

constexpr int D     = 32;    // D_WORLDS
constexpr int NW    = 512;   // N_WORLDS
constexpr int BATCH = 2048;
constexpr int TPB   = 128;   // 128 threads x 4 cols each = 512 cols

__global__ __launch_bounds__(TPB) void binop_kernel(
    const float* __restrict__ states,   // [8*2048, 32, 512]
    const float* __restrict__ W,        // [128, 32, 64]
    const float* __restrict__ b,        // [128, 32]
    const int*   __restrict__ indices,  // [2048]
    const int*   __restrict__ symbols,  // [2048]
    const int*   __restrict__ args,     // [2048, 2]
    float*       __restrict__ out)      // [2048, 32, 512]
{
    __shared__ float Wlds[D * 2 * D];   // [32][64] fp32 = 8 KB
    __shared__ float blds[D];

    const int n = blockIdx.x;
    const int t = threadIdx.x;

    const int sym = symbols[n];
    const int a0  = args[2 * n];
    const int a1  = args[2 * n + 1];
    const int idx = indices[n];

    // Stage W[sym] (2048 floats) + b[sym] (32 floats) into LDS, coalesced float4.
    {
        const float4* Wsym = (const float4*)(W + (size_t)sym * (D * 2 * D));
        float4* Wdst = (float4*)Wlds;
        #pragma unroll
        for (int i = 0; i < 4; ++i)
            Wdst[t + i * TPB] = Wsym[t + i * TPB];
        if (t < D) blds[t] = b[sym * D + t];
    }
    __syncthreads();

    const int w0 = t * 4;
    const float* lp = states + (size_t)(a0 * BATCH + idx) * (D * NW) + w0;
    const float* rp = states + (size_t)(a1 * BATCH + idx) * (D * NW) + w0;

    float4 acc[D];
    #pragma unroll
    for (int d = 0; d < D; ++d) acc[d] = make_float4(0.f, 0.f, 0.f, 0.f);

    // ---- left half: k in [0,32) -> W columns [0,32) ----
    #pragma unroll 2
    for (int k4 = 0; k4 < 8; ++k4) {
        const int k = k4 * 4;
        const float4 x0 = *(const float4*)(lp + (size_t)(k + 0) * NW);
        const float4 x1 = *(const float4*)(lp + (size_t)(k + 1) * NW);
        const float4 x2 = *(const float4*)(lp + (size_t)(k + 2) * NW);
        const float4 x3 = *(const float4*)(lp + (size_t)(k + 3) * NW);
        #pragma unroll
        for (int d = 0; d < D; ++d) {
            const float4 wv = *(const float4*)&Wlds[d * (2 * D) + k];
            acc[d].x += wv.x * x0.x + wv.y * x1.x + wv.z * x2.x + wv.w * x3.x;
            acc[d].y += wv.x * x0.y + wv.y * x1.y + wv.z * x2.y + wv.w * x3.y;
            acc[d].z += wv.x * x0.z + wv.y * x1.z + wv.z * x2.z + wv.w * x3.z;
            acc[d].w += wv.x * x0.w + wv.y * x1.w + wv.z * x2.w + wv.w * x3.w;
        }
    }

    // ---- right half: k in [0,32) -> W columns [32,64) ----
    #pragma unroll 2
    for (int k4 = 0; k4 < 8; ++k4) {
        const int k = k4 * 4;
        const float4 x0 = *(const float4*)(rp + (size_t)(k + 0) * NW);
        const float4 x1 = *(const float4*)(rp + (size_t)(k + 1) * NW);
        const float4 x2 = *(const float4*)(rp + (size_t)(k + 2) * NW);
        const float4 x3 = *(const float4*)(rp + (size_t)(k + 3) * NW);
        #pragma unroll
        for (int d = 0; d < D; ++d) {
            const float4 wv = *(const float4*)&Wlds[d * (2 * D) + D + k];
            acc[d].x += wv.x * x0.x + wv.y * x1.x + wv.z * x2.x + wv.w * x3.x;
            acc[d].y += wv.x * x0.y + wv.y * x1.y + wv.z * x2.y + wv.w * x3.y;
            acc[d].z += wv.x * x0.z + wv.y * x1.z + wv.z * x2.z + wv.w * x3.z;
            acc[d].w += wv.x * x0.w + wv.y * x1.w + wv.z * x2.w + wv.w * x3.w;
        }
    }

    // ---- bias + L2-normalize along d (thread-local: thread owns all 32 d's) ----
    float4 sq = make_float4(0.f, 0.f, 0.f, 0.f);
    #pragma unroll
    for (int d = 0; d < D; ++d) {
        const float bv = blds[d];
        acc[d].x += bv; acc[d].y += bv; acc[d].z += bv; acc[d].w += bv;
        sq.x += acc[d].x * acc[d].x;
        sq.y += acc[d].y * acc[d].y;
        sq.z += acc[d].z * acc[d].z;
        sq.w += acc[d].w * acc[d].w;
    }
    const float scx = rsqrtf(fmaxf(sq.x, 1e-12f));
    const float scy = rsqrtf(fmaxf(sq.y, 1e-12f));
    const float scz = rsqrtf(fmaxf(sq.z, 1e-12f));
    const float scw = rsqrtf(fmaxf(sq.w, 1e-12f));

    float* op = out + (size_t)idx * (D * NW) + w0;
    #pragma unroll
    for (int d = 0; d < D; ++d) {
        const float4 o = make_float4(acc[d].x * scx, acc[d].y * scy,
                                     acc[d].z * scz, acc[d].w * scw);
        *(float4*)(op + (size_t)d * NW) = o;
    }
}

extern "C" void kernel_launch(void* const* d_in, const int* in_sizes, int n_in,
                              void* d_out, int out_size, void* d_ws, size_t ws_size,
                              hipStream_t stream) {
    const float* states  = (const float*)d_in[0];
    const float* W       = (const float*)d_in[1];
    const float* b       = (const float*)d_in[2];
    const int*   indices = (const int*)d_in[3];
    const int*   symbols = (const int*)d_in[4];
    const int*   args    = (const int*)d_in[5];
    float*       out     = (float*)d_out;

    binop_kernel<<<dim3(BATCH), dim3(TPB), 0, stream>>>(
        states, W, b, indices, symbols, args, out);
}